// Round 9
// baseline (362.286 us; speedup 1.0000x reference)
//
#include <hip/hip_runtime.h>
#include <stdint.h>

typedef unsigned int  uint32;
typedef unsigned short u16;

typedef short bfx8 __attribute__((ext_vector_type(8)));
typedef float f32x4 __attribute__((ext_vector_type(4)));
typedef float f32x2 __attribute__((ext_vector_type(2)));

#define NBP 256          // padded bucket count (N <= 65536)
#define CH  2048         // edges per partition chunk
#define BS  4608         // fixed slots per bucket (mean 4096, sigma~64 -> 8-sigma margin)

// ---------- bf16 helpers ----------
__device__ __forceinline__ float b2f(u16 u) {
    union { uint32 i; float f; } v; v.i = ((uint32)u) << 16; return v.f;
}
__device__ __forceinline__ u16 f2b(float f) {
    union { float f; uint32 i; } v; v.f = f;
    uint32 u = v.i;
    return (u16)((u + 0x7fffu + ((u >> 16) & 1u)) >> 16);   // RNE
}
__device__ __forceinline__ float blo(uint32 u) {
    union { uint32 i; float f; } v; v.i = u << 16; return v.f;
}
__device__ __forceinline__ float bhi(uint32 u) {
    union { uint32 i; float f; } v; v.i = u & 0xffff0000u; return v.f;
}
__device__ __forceinline__ uint32 packbf(float a, float b) {
    return (uint32)f2b(a) | ((uint32)f2b(b) << 16);
}
__device__ __forceinline__ void splitf(float x, u16& h, u16& l) {
    h = f2b(x);
    l = f2b(x - b2f(h));
}

// ---------- init: block 0 sets bucket cursors; other blocks split weights ----------
__global__ __launch_bounds__(256) void k_init(
    int* __restrict__ curC, int* __restrict__ curR,
    const float* __restrict__ W1, const float* __restrict__ W2,
    const float* __restrict__ W3, const float* __restrict__ fcW,
    u16* __restrict__ WTh, u16* __restrict__ WTl, int WTN) {
    int t = threadIdx.x;
    if (blockIdx.x == 0) {
        curC[t] = t * BS;
        curR[t] = t * BS;
        return;
    }
    int i = ((int)blockIdx.x - 1) * 256 + t;
    if (i >= WTN) return;
    float w;
    if (i < 3 * 16384) {
        int m = i >> 14, j = i & 16383;     // j = fo*128 + fi
        int fo = j >> 7, fi = j & 127;
        const float* W = (m == 0) ? W1 : (m == 1) ? W2 : W3;
        w = W[fi * 128 + fo];
    } else {
        int j = i - 3 * 16384;
        int fo = j >> 7, fi = j & 127;
        w = fcW[fi * 64 + fo];
    }
    u16 h, l; splitf(w, h, l);
    WTh[i] = h; WTl[i] = l;
}

// ---------- pass C: dual-direction bucket partition into fixed-stride regions ---------
__global__ __launch_bounds__(256) void k_partC(
    const int* __restrict__ row, const int* __restrict__ col, int E,
    int* __restrict__ curC, int* __restrict__ curR,
    uint32* __restrict__ partC, uint32* __restrict__ partR) {
    __shared__ uint32 stagedC[CH], stagedR[CH];
    __shared__ int hp[NBP], expk[NBP], curp[NBP], runC[NBP], runR[NBP];
    __shared__ int wsum[4];
    int t = threadIdx.x;
    int lane = t & 63, wid = t >> 6;
    int base = blockIdx.x * CH;
    int n = E - base; if (n > CH) n = CH;

    int er[8], ec[8];
#pragma unroll
    for (int j = 0; j < 8; ++j) {
        int i = t + j * 256;
        if (i < n) { er[j] = row[base + i]; ec[j] = col[base + i]; }
        else er[j] = -1;
    }
    hp[t] = 0;
    __syncthreads();
#pragma unroll
    for (int j = 0; j < 8; ++j) {
        if (er[j] >= 0) {
            atomicAdd(&hp[ec[j] >> 8], 1);
            atomicAdd(&hp[er[j] >> 8], 0x10000);
        }
    }
    __syncthreads();
    int v = hp[t];
    int x = v;
#pragma unroll
    for (int d = 1; d < 64; d <<= 1) {
        int u = __shfl_up(x, d);
        if (lane >= d) x += u;
    }
    if (lane == 63) wsum[wid] = x;
    __syncthreads();
    int add = 0;
    for (int i = 0; i < wid; ++i) add += wsum[i];
    int ex = x + add - v;
    expk[t] = ex;
    curp[t] = ex;
    int vC = v & 0xffff, vR = v >> 16;
    runC[t] = vC ? atomicAdd(&curC[t], vC) : 0;
    runR[t] = vR ? atomicAdd(&curR[t], vR) : 0;
    __syncthreads();
#pragma unroll
    for (int j = 0; j < 8; ++j) {
        if (er[j] >= 0) {
            int cb = ec[j] >> 8, rb = er[j] >> 8;
            int pC = atomicAdd(&curp[cb], 1) & 0xffff;
            stagedC[pC] = ((uint32)ec[j] << 16) | (uint32)er[j];
            int pR = atomicAdd(&curp[rb], 0x10000) >> 16;
            stagedR[pR] = ((uint32)er[j] << 16) | (uint32)ec[j];
        }
    }
    __syncthreads();
    for (int i = t; i < n; i += 256) {
        uint32 pv = stagedC[i];
        int b = pv >> 24;
        partC[runC[b] + (i - (expk[b] & 0xffff))] = pv;
    }
    for (int i = t; i < n; i += 256) {
        uint32 pv = stagedR[i];
        int b = pv >> 24;
        partR[runR[b] + (i - (expk[b] >> 16))] = pv;
    }
}

// ---------- pass D: per-bucket CSR fill + per-node (start,end) + dinv ----------
__global__ __launch_bounds__(256) void k_fillD(
    const uint32* __restrict__ partC, const uint32* __restrict__ partR,
    const int* __restrict__ curC, const int* __restrict__ curR,
    int* __restrict__ off_in, int* __restrict__ end_in,
    int* __restrict__ off_out, int* __restrict__ end_out,
    u16* __restrict__ csr_src, u16* __restrict__ csr_dst,
    float* __restrict__ dinv, int NB, int N) {
    int part = ((int)blockIdx.x >= NB) ? 1 : 0;
    int b = (int)blockIdx.x - part * NB;
    const uint32* arr = part ? partR : partC;
    const int* curA   = part ? curR : curC;
    int* offA         = part ? off_out : off_in;
    int* endA         = part ? end_out : end_in;
    u16* csr          = part ? csr_dst : csr_src;
    int t = threadIdx.x;
    int lane = t & 63, wid = t >> 6;
    int base = b * BS, end = curA[b];
    __shared__ int cnt[NBP], cur[NBP];
    __shared__ int wsum[4];
    cnt[t] = 0;
    __syncthreads();
    for (int i = base + t; i < end; i += 256)
        atomicAdd(&cnt[(arr[i] >> 16) & 255], 1);
    __syncthreads();
    int v = cnt[t];
    int x = v;
#pragma unroll
    for (int d = 1; d < 64; d <<= 1) {
        int u = __shfl_up(x, d);
        if (lane >= d) x += u;
    }
    if (lane == 63) wsum[wid] = x;
    __syncthreads();
    int add = 0;
    for (int i = 0; i < wid; ++i) add += wsum[i];
    int ex = x + add - v;
    cur[t] = ex;
    int node = (b << 8) + t;
    if (node < N) {
        offA[node] = base + ex;
        endA[node] = base + ex + v;
        if (part == 0) dinv[node] = rsqrtf((float)(v + 1));   // in-degree + self loop
    }
    __syncthreads();
    for (int i = base + t; i < end; i += 256) {
        uint32 pv = arr[i];
        int local = (pv >> 16) & 255;
        int pos = atomicAdd(&cur[local], 1);
        csr[base + pos] = (u16)(pv & 0xffffu);
    }
}

// ---------- gemm0 (fp32 A, single-plane bf16 cast): G = (A @ W) * dinv, bf16 out ------
__global__ __launch_bounds__(256) void k_gemm0(
    const float* __restrict__ A, const u16* __restrict__ WTh, const u16* __restrict__ WTl,
    const float* __restrict__ dinv, u16* __restrict__ G, int M) {
    const int lane = threadIdx.x & 63;
    const int q = lane >> 4, l = lane & 15;
    int rbase = blockIdx.x * 128 + (threadIdx.x >> 6) * 32;
    if (rbase >= M) return;
    int r0 = rbase + l;      if (r0 >= M) r0 = M - 1;
    int r1 = rbase + 16 + l; if (r1 >= M) r1 = M - 1;

    f32x4 acc[2][8];
#pragma unroll
    for (int i = 0; i < 2; ++i)
#pragma unroll
        for (int j = 0; j < 8; ++j) acc[i][j] = (f32x4){0.f, 0.f, 0.f, 0.f};

#pragma unroll
    for (int kc = 0; kc < 4; ++kc) {
        int k0 = kc * 32 + q * 8;
        bfx8 ah0, ah1;
        {
            f32x4 a = *(const f32x4*)(A + (size_t)r0 * 128 + k0);
            f32x4 b = *(const f32x4*)(A + (size_t)r0 * 128 + k0 + 4);
            float xx[8] = {a[0], a[1], a[2], a[3], b[0], b[1], b[2], b[3]};
#pragma unroll
            for (int j = 0; j < 8; ++j) ah0[j] = (short)f2b(xx[j]);
        }
        {
            f32x4 a = *(const f32x4*)(A + (size_t)r1 * 128 + k0);
            f32x4 b = *(const f32x4*)(A + (size_t)r1 * 128 + k0 + 4);
            float xx[8] = {a[0], a[1], a[2], a[3], b[0], b[1], b[2], b[3]};
#pragma unroll
            for (int j = 0; j < 8; ++j) ah1[j] = (short)f2b(xx[j]);
        }
#pragma unroll
        for (int ct = 0; ct < 8; ++ct) {
            bfx8 bh = *(const bfx8*)(WTh + (ct * 16 + l) * 128 + k0);
            bfx8 bl = *(const bfx8*)(WTl + (ct * 16 + l) * 128 + k0);
            acc[0][ct] = __builtin_amdgcn_mfma_f32_16x16x32_bf16(ah0, bh, acc[0][ct], 0, 0, 0);
            acc[0][ct] = __builtin_amdgcn_mfma_f32_16x16x32_bf16(ah0, bl, acc[0][ct], 0, 0, 0);
            acc[1][ct] = __builtin_amdgcn_mfma_f32_16x16x32_bf16(ah1, bh, acc[1][ct], 0, 0, 0);
            acc[1][ct] = __builtin_amdgcn_mfma_f32_16x16x32_bf16(ah1, bl, acc[1][ct], 0, 0, 0);
        }
    }
#pragma unroll
    for (int rs = 0; rs < 2; ++rs) {
#pragma unroll
        for (int rr = 0; rr < 4; ++rr) {
            int rw = rbase + rs * 16 + q * 4 + rr;
            if (rw < M) {
                float dv = dinv[rw];
#pragma unroll
                for (int ct = 0; ct < 8; ++ct)
                    G[(size_t)rw * 128 + ct * 16 + l] = f2b(acc[rs][ct][rr] * dv);
            }
        }
    }
}

// ---------- gemm, single bf16-plane A: G = (A @ W) * dinv, bf16 out ----------
__global__ __launch_bounds__(256) void k_gemm1p(
    const u16* __restrict__ Ah,
    const u16* __restrict__ WTh, const u16* __restrict__ WTl,
    const float* __restrict__ dinv, u16* __restrict__ G, int M) {
    const int lane = threadIdx.x & 63;
    const int q = lane >> 4, l = lane & 15;
    int rbase = blockIdx.x * 128 + (threadIdx.x >> 6) * 32;
    if (rbase >= M) return;
    int r0 = rbase + l;      if (r0 >= M) r0 = M - 1;
    int r1 = rbase + 16 + l; if (r1 >= M) r1 = M - 1;

    f32x4 acc[2][8];
#pragma unroll
    for (int i = 0; i < 2; ++i)
#pragma unroll
        for (int j = 0; j < 8; ++j) acc[i][j] = (f32x4){0.f, 0.f, 0.f, 0.f};

#pragma unroll
    for (int kc = 0; kc < 4; ++kc) {
        int k0 = kc * 32 + q * 8;
        bfx8 ah0 = *(const bfx8*)(Ah + (size_t)r0 * 128 + k0);
        bfx8 ah1 = *(const bfx8*)(Ah + (size_t)r1 * 128 + k0);
#pragma unroll
        for (int ct = 0; ct < 8; ++ct) {
            bfx8 bh = *(const bfx8*)(WTh + (ct * 16 + l) * 128 + k0);
            bfx8 bl = *(const bfx8*)(WTl + (ct * 16 + l) * 128 + k0);
            acc[0][ct] = __builtin_amdgcn_mfma_f32_16x16x32_bf16(ah0, bh, acc[0][ct], 0, 0, 0);
            acc[0][ct] = __builtin_amdgcn_mfma_f32_16x16x32_bf16(ah0, bl, acc[0][ct], 0, 0, 0);
            acc[1][ct] = __builtin_amdgcn_mfma_f32_16x16x32_bf16(ah1, bh, acc[1][ct], 0, 0, 0);
            acc[1][ct] = __builtin_amdgcn_mfma_f32_16x16x32_bf16(ah1, bl, acc[1][ct], 0, 0, 0);
        }
    }
#pragma unroll
    for (int rs = 0; rs < 2; ++rs) {
#pragma unroll
        for (int rr = 0; rr < 4; ++rr) {
            int rw = rbase + rs * 16 + q * 4 + rr;
            if (rw < M) {
                float dv = dinv[rw];
#pragma unroll
                for (int ct = 0; ct < 8; ++ct)
                    G[(size_t)rw * 128 + ct * 16 + l] = f2b(acc[rs][ct][rr] * dv);
            }
        }
    }
}

// ---------- GCN aggregate: wave = 2 half-waves x 32 lanes, 2 neighbor rows / instr ----
// g pre-scaled by dinv[src]; out[c] = relu(dinv[c]*(g[c] + sum g[src]) + b), bf16 out
__global__ __launch_bounds__(256) void k_agg(
    const uint2* __restrict__ g2, const u16* __restrict__ csr,
    const int* __restrict__ off, const int* __restrict__ endo,
    const float* __restrict__ dinv, const f32x4* __restrict__ bias4,
    uint2* __restrict__ outH, int n) {
    int w = (blockIdx.x * 256 + threadIdx.x) >> 6;
    if (w >= n) return;
    int lane = threadIdx.x & 63;
    int half = lane >> 5, sl = lane & 31;
    uint2 sv = g2[(size_t)w * 32 + sl];
    float s0, s1, s2, s3;
    if (half == 0) { s0 = blo(sv.x); s1 = bhi(sv.x); s2 = blo(sv.y); s3 = bhi(sv.y); }
    else           { s0 = s1 = s2 = s3 = 0.f; }
    int e = off[w], e1 = endo[w];
    int deg = e1 - e;
    int pairs = deg >> 1;
    int p = 0;
    for (; p + 8 <= pairs; p += 8) {
        int ix[8];
#pragma unroll
        for (int j = 0; j < 8; ++j) ix[j] = csr[e + 2 * (p + j) + half];
        uint2 vv[8];
#pragma unroll
        for (int j = 0; j < 8; ++j) vv[j] = g2[(size_t)ix[j] * 32 + sl];
#pragma unroll
        for (int j = 0; j < 8; ++j) {
            s0 += blo(vv[j].x); s1 += bhi(vv[j].x);
            s2 += blo(vv[j].y); s3 += bhi(vv[j].y);
        }
    }
    for (; p < pairs; ++p) {
        int ix = csr[e + 2 * p + half];
        uint2 vv = g2[(size_t)ix * 32 + sl];
        s0 += blo(vv.x); s1 += bhi(vv.x);
        s2 += blo(vv.y); s3 += bhi(vv.y);
    }
    if (deg & 1) {
        int ix = csr[e1 - 1];
        uint2 vv = g2[(size_t)ix * 32 + sl];
        if (half == 0) {
            s0 += blo(vv.x); s1 += bhi(vv.x);
            s2 += blo(vv.y); s3 += bhi(vv.y);
        }
    }
    s0 += __shfl_xor(s0, 32);
    s1 += __shfl_xor(s1, 32);
    s2 += __shfl_xor(s2, 32);
    s3 += __shfl_xor(s3, 32);
    if (half) return;
    float dc = dinv[w];
    f32x4 bb = bias4[sl];
    float o0 = fmaxf(fmaf(s0, dc, bb[0]), 0.f);
    float o1 = fmaxf(fmaf(s1, dc, bb[1]), 0.f);
    float o2 = fmaxf(fmaf(s2, dc, bb[2]), 0.f);
    float o3 = fmaxf(fmaf(s3, dc, bb[3]), 0.f);
    uint2 o; o.x = packbf(o0, o1); o.y = packbf(o2, o3);
    outH[(size_t)w * 32 + sl] = o;
}

// ---------- neighbor mean: same pair-gather structure, bf16 out ----------
__global__ __launch_bounds__(256) void k_mean(
    const uint2* __restrict__ h2, const u16* __restrict__ csr,
    const int* __restrict__ off, const int* __restrict__ endo,
    uint2* __restrict__ outH, int n) {
    int w = (blockIdx.x * 256 + threadIdx.x) >> 6;
    if (w >= n) return;
    int lane = threadIdx.x & 63;
    int half = lane >> 5, sl = lane & 31;
    int e = off[w], e1 = endo[w];
    int deg = e1 - e;
    float s0 = 0.f, s1 = 0.f, s2 = 0.f, s3 = 0.f;
    int pairs = deg >> 1;
    int p = 0;
    for (; p + 8 <= pairs; p += 8) {
        int ix[8];
#pragma unroll
        for (int j = 0; j < 8; ++j) ix[j] = csr[e + 2 * (p + j) + half];
        uint2 vv[8];
#pragma unroll
        for (int j = 0; j < 8; ++j) vv[j] = h2[(size_t)ix[j] * 32 + sl];
#pragma unroll
        for (int j = 0; j < 8; ++j) {
            s0 += blo(vv[j].x); s1 += bhi(vv[j].x);
            s2 += blo(vv[j].y); s3 += bhi(vv[j].y);
        }
    }
    for (; p < pairs; ++p) {
        int ix = csr[e + 2 * p + half];
        uint2 vv = h2[(size_t)ix * 32 + sl];
        s0 += blo(vv.x); s1 += bhi(vv.x);
        s2 += blo(vv.y); s3 += bhi(vv.y);
    }
    if (deg & 1) {
        int ix = csr[e1 - 1];
        uint2 vv = h2[(size_t)ix * 32 + sl];
        if (half == 0) {
            s0 += blo(vv.x); s1 += bhi(vv.x);
            s2 += blo(vv.y); s3 += bhi(vv.y);
        }
    }
    s0 += __shfl_xor(s0, 32);
    s1 += __shfl_xor(s1, 32);
    s2 += __shfl_xor(s2, 32);
    s3 += __shfl_xor(s3, 32);
    if (half) return;
    float o0, o1, o2, o3;
    if (deg > 0) {
        float inv = 1.f / (float)deg;
        o0 = s0 * inv; o1 = s1 * inv; o2 = s2 * inv; o3 = s3 * inv;
    } else {
        uint2 sv = h2[(size_t)w * 32 + sl];
        o0 = blo(sv.x); o1 = bhi(sv.x); o2 = blo(sv.y); o3 = bhi(sv.y);
    }
    uint2 o; o.x = packbf(o0, o1); o.y = packbf(o2, o3);
    outH[(size_t)w * 32 + sl] = o;
}

// ---------- final: out = (w0*h0 + w1*h1 + w2*h2) @ fcW + fc_b ----------
__global__ __launch_bounds__(256) void k_final(
    const u16* __restrict__ h0, const u16* __restrict__ h1,
    const u16* __restrict__ h2, const float* __restrict__ jkw,
    const u16* __restrict__ fcWTh, const u16* __restrict__ fcWTl,
    const float* __restrict__ fcb, float* __restrict__ out, int M) {
    float a0 = jkw[0], a1 = jkw[1], a2 = jkw[2];
    float mx = fmaxf(a0, fmaxf(a1, a2));
    float e0 = expf(a0 - mx), e1 = expf(a1 - mx), e2 = expf(a2 - mx);
    float inv = 1.f / (e0 + e1 + e2);
    float w0 = e0 * inv, w1 = e1 * inv, w2 = e2 * inv;

    const int lane = threadIdx.x & 63;
    const int q = lane >> 4, l = lane & 15;
    int rbase = blockIdx.x * 128 + (threadIdx.x >> 6) * 32;
    if (rbase >= M) return;
    int r0 = rbase + l;      if (r0 >= M) r0 = M - 1;
    int r1 = rbase + 16 + l; if (r1 >= M) r1 = M - 1;

    f32x4 acc[2][4];
#pragma unroll
    for (int i = 0; i < 2; ++i)
#pragma unroll
        for (int j = 0; j < 4; ++j) acc[i][j] = (f32x4){0.f, 0.f, 0.f, 0.f};

    union U8 { bfx8 v; u16 u[8]; };

#pragma unroll
    for (int kc = 0; kc < 4; ++kc) {
        int k0 = kc * 32 + q * 8;
        bfx8 ah[2];
        const int rr2[2] = {r0, r1};
#pragma unroll
        for (int half = 0; half < 2; ++half) {
            size_t o = (size_t)rr2[half] * 128 + k0;
            U8 x0, x1, x2, rh;
            x0.v = *(const bfx8*)(h0 + o);
            x1.v = *(const bfx8*)(h1 + o);
            x2.v = *(const bfx8*)(h2 + o);
#pragma unroll
            for (int j = 0; j < 8; ++j) {
                float c = w0 * b2f(x0.u[j]) + w1 * b2f(x1.u[j]) + w2 * b2f(x2.u[j]);
                rh.u[j] = f2b(c);
            }
            ah[half] = rh.v;
        }
#pragma unroll
        for (int ct = 0; ct < 4; ++ct) {
            bfx8 bh = *(const bfx8*)(fcWTh + (ct * 16 + l) * 128 + k0);
            bfx8 bl = *(const bfx8*)(fcWTl + (ct * 16 + l) * 128 + k0);
#pragma unroll
            for (int half = 0; half < 2; ++half) {
                acc[half][ct] = __builtin_amdgcn_mfma_f32_16x16x32_bf16(ah[half], bh, acc[half][ct], 0, 0, 0);
                acc[half][ct] = __builtin_amdgcn_mfma_f32_16x16x32_bf16(ah[half], bl, acc[half][ct], 0, 0, 0);
            }
        }
    }
#pragma unroll
    for (int rs = 0; rs < 2; ++rs) {
#pragma unroll
        for (int rr = 0; rr < 4; ++rr) {
            int rw = rbase + rs * 16 + q * 4 + rr;
            if (rw < M) {
#pragma unroll
                for (int ct = 0; ct < 4; ++ct) {
                    int cc = ct * 16 + l;
                    out[(size_t)rw * 64 + cc] = acc[rs][ct][rr] + fcb[cc];
                }
            }
        }
    }
}

extern "C" void kernel_launch(void* const* d_in, const int* in_sizes, int n_in,
                              void* d_out, int out_size, void* d_ws, size_t ws_size,
                              hipStream_t stream) {
    const int N = in_sizes[0] / 128;   // 50000
    const int E = in_sizes[1] / 2;     // 800000
    const int NB = (N + 255) >> 8;     // 196 buckets

    const float* x    = (const float*)d_in[0];
    const int* row    = (const int*)d_in[1];
    const int* col    = row + E;
    const float* W1   = (const float*)d_in[2];
    const float* b1   = (const float*)d_in[3];
    const float* W2   = (const float*)d_in[4];
    const float* b2   = (const float*)d_in[5];
    const float* W3   = (const float*)d_in[6];
    const float* b3   = (const float*)d_in[7];
    const float* jkw  = (const float*)d_in[8];
    const float* fcW  = (const float*)d_in[9];
    const float* fcb  = (const float*)d_in[10];
    float* outp       = (float*)d_out;

    char* ws = (char*)d_ws;
    size_t off = 0;
    auto alloc = [&](size_t bytes) -> char* {
        char* p = ws + off;
        off += (bytes + 255) & ~(size_t)255;
        return p;
    };
    int* curC   = (int*)alloc((size_t)NBP * sizeof(int));
    int* curR   = (int*)alloc((size_t)NBP * sizeof(int));
    int* off_in  = (int*)alloc((size_t)N * sizeof(int));
    int* end_in  = (int*)alloc((size_t)N * sizeof(int));
    int* off_out = (int*)alloc((size_t)N * sizeof(int));
    int* end_out = (int*)alloc((size_t)N * sizeof(int));
    uint32* partC = (uint32*)alloc((size_t)NBP * BS * sizeof(uint32));
    uint32* partR = (uint32*)alloc((size_t)NBP * BS * sizeof(uint32));
    u16* csr_src = (u16*)alloc((size_t)NBP * BS * sizeof(u16));
    u16* csr_dst = (u16*)alloc((size_t)NBP * BS * sizeof(u16));
    float* dinv  = (float*)alloc((size_t)N * sizeof(float));
    const int WTN = 3 * 16384 + 8192;
    u16* WTh = (u16*)alloc((size_t)WTN * sizeof(u16));
    u16* WTl = (u16*)alloc((size_t)WTN * sizeof(u16));
    size_t FB = (size_t)N * 128 * sizeof(u16);
    u16* gbuf = (u16*)alloc(FB);
    u16* t0   = (u16*)alloc(FB);
    u16* h0   = (u16*)alloc(FB);
    u16* h1   = (u16*)alloc(FB);
    u16* h2   = (u16*)alloc(FB);

    const int B = 256;
    int Gh = (E + CH - 1) / CH;
    int Gg = (N + 127) / 128;
    int Gwt = (WTN + B - 1) / B;

    k_init<<<1 + Gwt, B, 0, stream>>>(curC, curR, W1, W2, W3, fcW, WTh, WTl, WTN);
    k_partC<<<Gh, B, 0, stream>>>(row, col, E, curC, curR, partC, partR);
    k_fillD<<<2 * NB, B, 0, stream>>>(partC, partR, curC, curR,
                                      off_in, end_in, off_out, end_out,
                                      csr_src, csr_dst, dinv, NB, N);
    k_gemm0<<<Gg, B, 0, stream>>>(x, WTh, WTl, dinv, gbuf, N);

    int aggG = (N + 3) / 4;            // 4 waves/block, 1 node/wave

    // layer 0
    k_agg<<<aggG, B, 0, stream>>>((const uint2*)gbuf, csr_src, off_in, end_in, dinv,
                                  (const f32x4*)b1, (uint2*)t0, N);
    k_mean<<<aggG, B, 0, stream>>>((const uint2*)t0, csr_dst, off_out, end_out,
                                   (uint2*)h0, N);
    // layer 1
    k_gemm1p<<<Gg, B, 0, stream>>>(h0, WTh + 16384, WTl + 16384, dinv, gbuf, N);
    k_agg<<<aggG, B, 0, stream>>>((const uint2*)gbuf, csr_src, off_in, end_in, dinv,
                                  (const f32x4*)b2, (uint2*)h1, N);
    // layer 2
    k_gemm1p<<<Gg, B, 0, stream>>>(h1, WTh + 2 * 16384, WTl + 2 * 16384, dinv, gbuf, N);
    k_agg<<<aggG, B, 0, stream>>>((const uint2*)gbuf, csr_src, off_in, end_in, dinv,
                                  (const f32x4*)b3, (uint2*)h2, N);
    // JK combine + final linear
    k_final<<<Gg, B, 0, stream>>>(h0, h1, h2, jkw,
                                  WTh + 3 * 16384, WTl + 3 * 16384, fcb, outp, N);
}

// Round 10
// 334.993 us; speedup vs baseline: 1.0815x; 1.0815x over previous
//
#include <hip/hip_runtime.h>
#include <stdint.h>

typedef unsigned int  uint32;
typedef unsigned short u16;

typedef short bfx8 __attribute__((ext_vector_type(8)));
typedef float f32x4 __attribute__((ext_vector_type(4)));
typedef float f32x2 __attribute__((ext_vector_type(2)));

#define NBP 256          // padded bucket count (N <= 65536)
#define CH  2048         // edges per partition chunk
#define BS  4608         // fixed slots per bucket (mean 4096, sigma~64 -> 8-sigma margin)

// ---------- bf16 helpers ----------
__device__ __forceinline__ float b2f(u16 u) {
    union { uint32 i; float f; } v; v.i = ((uint32)u) << 16; return v.f;
}
__device__ __forceinline__ u16 f2b(float f) {
    union { float f; uint32 i; } v; v.f = f;
    uint32 u = v.i;
    return (u16)((u + 0x7fffu + ((u >> 16) & 1u)) >> 16);   // RNE
}
__device__ __forceinline__ float blo(uint32 u) {
    union { uint32 i; float f; } v; v.i = u << 16; return v.f;
}
__device__ __forceinline__ float bhi(uint32 u) {
    union { uint32 i; float f; } v; v.i = u & 0xffff0000u; return v.f;
}
__device__ __forceinline__ uint32 packbf(float a, float b) {
    return (uint32)f2b(a) | ((uint32)f2b(b) << 16);
}
__device__ __forceinline__ void splitf(float x, u16& h, u16& l) {
    h = f2b(x);
    l = f2b(x - b2f(h));
}

// ---------- init: block 0 sets bucket cursors; other blocks split weights ----------
__global__ __launch_bounds__(256) void k_init(
    int* __restrict__ curC, int* __restrict__ curR,
    const float* __restrict__ W1, const float* __restrict__ W2,
    const float* __restrict__ W3, const float* __restrict__ fcW,
    u16* __restrict__ WTh, u16* __restrict__ WTl, int WTN) {
    int t = threadIdx.x;
    if (blockIdx.x == 0) {
        curC[t] = t * BS;
        curR[t] = t * BS;
        return;
    }
    int i = ((int)blockIdx.x - 1) * 256 + t;
    if (i >= WTN) return;
    float w;
    if (i < 3 * 16384) {
        int m = i >> 14, j = i & 16383;     // j = fo*128 + fi
        int fo = j >> 7, fi = j & 127;
        const float* W = (m == 0) ? W1 : (m == 1) ? W2 : W3;
        w = W[fi * 128 + fo];
    } else {
        int j = i - 3 * 16384;
        int fo = j >> 7, fi = j & 127;
        w = fcW[fi * 64 + fo];
    }
    u16 h, l; splitf(w, h, l);
    WTh[i] = h; WTl[i] = l;
}

// ---------- pass C: dual-direction bucket partition into fixed-stride regions ---------
__global__ __launch_bounds__(256) void k_partC(
    const int* __restrict__ row, const int* __restrict__ col, int E,
    int* __restrict__ curC, int* __restrict__ curR,
    uint32* __restrict__ partC, uint32* __restrict__ partR) {
    __shared__ uint32 stagedC[CH], stagedR[CH];
    __shared__ int hp[NBP], expk[NBP], curp[NBP], runC[NBP], runR[NBP];
    __shared__ int wsum[4];
    int t = threadIdx.x;
    int lane = t & 63, wid = t >> 6;
    int base = blockIdx.x * CH;
    int n = E - base; if (n > CH) n = CH;

    int er[8], ec[8];
#pragma unroll
    for (int j = 0; j < 8; ++j) {
        int i = t + j * 256;
        if (i < n) { er[j] = row[base + i]; ec[j] = col[base + i]; }
        else er[j] = -1;
    }
    hp[t] = 0;
    __syncthreads();
#pragma unroll
    for (int j = 0; j < 8; ++j) {
        if (er[j] >= 0) {
            atomicAdd(&hp[ec[j] >> 8], 1);
            atomicAdd(&hp[er[j] >> 8], 0x10000);
        }
    }
    __syncthreads();
    int v = hp[t];
    int x = v;
#pragma unroll
    for (int d = 1; d < 64; d <<= 1) {
        int u = __shfl_up(x, d);
        if (lane >= d) x += u;
    }
    if (lane == 63) wsum[wid] = x;
    __syncthreads();
    int add = 0;
    for (int i = 0; i < wid; ++i) add += wsum[i];
    int ex = x + add - v;
    expk[t] = ex;
    curp[t] = ex;
    int vC = v & 0xffff, vR = v >> 16;
    runC[t] = vC ? atomicAdd(&curC[t], vC) : 0;
    runR[t] = vR ? atomicAdd(&curR[t], vR) : 0;
    __syncthreads();
#pragma unroll
    for (int j = 0; j < 8; ++j) {
        if (er[j] >= 0) {
            int cb = ec[j] >> 8, rb = er[j] >> 8;
            int pC = atomicAdd(&curp[cb], 1) & 0xffff;
            stagedC[pC] = ((uint32)ec[j] << 16) | (uint32)er[j];
            int pR = atomicAdd(&curp[rb], 0x10000) >> 16;
            stagedR[pR] = ((uint32)er[j] << 16) | (uint32)ec[j];
        }
    }
    __syncthreads();
    for (int i = t; i < n; i += 256) {
        uint32 pv = stagedC[i];
        int b = pv >> 24;
        partC[runC[b] + (i - (expk[b] & 0xffff))] = pv;
    }
    for (int i = t; i < n; i += 256) {
        uint32 pv = stagedR[i];
        int b = pv >> 24;
        partR[runR[b] + (i - (expk[b] >> 16))] = pv;
    }
}

// ---------- pass D: per-bucket CSR fill + per-node (start,end) + dinv ----------
__global__ __launch_bounds__(256) void k_fillD(
    const uint32* __restrict__ partC, const uint32* __restrict__ partR,
    const int* __restrict__ curC, const int* __restrict__ curR,
    int* __restrict__ off_in, int* __restrict__ end_in,
    int* __restrict__ off_out, int* __restrict__ end_out,
    u16* __restrict__ csr_src, u16* __restrict__ csr_dst,
    float* __restrict__ dinv, int NB, int N) {
    int part = ((int)blockIdx.x >= NB) ? 1 : 0;
    int b = (int)blockIdx.x - part * NB;
    const uint32* arr = part ? partR : partC;
    const int* curA   = part ? curR : curC;
    int* offA         = part ? off_out : off_in;
    int* endA         = part ? end_out : end_in;
    u16* csr          = part ? csr_dst : csr_src;
    int t = threadIdx.x;
    int lane = t & 63, wid = t >> 6;
    int base = b * BS, end = curA[b];
    __shared__ int cnt[NBP], cur[NBP];
    __shared__ int wsum[4];
    cnt[t] = 0;
    __syncthreads();
    for (int i = base + t; i < end; i += 256)
        atomicAdd(&cnt[(arr[i] >> 16) & 255], 1);
    __syncthreads();
    int v = cnt[t];
    int x = v;
#pragma unroll
    for (int d = 1; d < 64; d <<= 1) {
        int u = __shfl_up(x, d);
        if (lane >= d) x += u;
    }
    if (lane == 63) wsum[wid] = x;
    __syncthreads();
    int add = 0;
    for (int i = 0; i < wid; ++i) add += wsum[i];
    int ex = x + add - v;
    cur[t] = ex;
    int node = (b << 8) + t;
    if (node < N) {
        offA[node] = base + ex;
        endA[node] = base + ex + v;
        if (part == 0) dinv[node] = rsqrtf((float)(v + 1));   // in-degree + self loop
    }
    __syncthreads();
    for (int i = base + t; i < end; i += 256) {
        uint32 pv = arr[i];
        int local = (pv >> 16) & 255;
        int pos = atomicAdd(&cur[local], 1);
        csr[base + pos] = (u16)(pv & 0xffffu);
    }
}

// ---------- gemm0 (fp32 A, single-plane bf16 cast): G = (A @ W) * dinv, bf16 out ------
__global__ __launch_bounds__(256) void k_gemm0(
    const float* __restrict__ A, const u16* __restrict__ WTh, const u16* __restrict__ WTl,
    const float* __restrict__ dinv, u16* __restrict__ G, int M) {
    const int lane = threadIdx.x & 63;
    const int q = lane >> 4, l = lane & 15;
    int rbase = blockIdx.x * 128 + (threadIdx.x >> 6) * 32;
    if (rbase >= M) return;
    int r0 = rbase + l;      if (r0 >= M) r0 = M - 1;
    int r1 = rbase + 16 + l; if (r1 >= M) r1 = M - 1;

    f32x4 acc[2][8];
#pragma unroll
    for (int i = 0; i < 2; ++i)
#pragma unroll
        for (int j = 0; j < 8; ++j) acc[i][j] = (f32x4){0.f, 0.f, 0.f, 0.f};

#pragma unroll
    for (int kc = 0; kc < 4; ++kc) {
        int k0 = kc * 32 + q * 8;
        bfx8 ah0, ah1;
        {
            f32x4 a = *(const f32x4*)(A + (size_t)r0 * 128 + k0);
            f32x4 b = *(const f32x4*)(A + (size_t)r0 * 128 + k0 + 4);
            float xx[8] = {a[0], a[1], a[2], a[3], b[0], b[1], b[2], b[3]};
#pragma unroll
            for (int j = 0; j < 8; ++j) ah0[j] = (short)f2b(xx[j]);
        }
        {
            f32x4 a = *(const f32x4*)(A + (size_t)r1 * 128 + k0);
            f32x4 b = *(const f32x4*)(A + (size_t)r1 * 128 + k0 + 4);
            float xx[8] = {a[0], a[1], a[2], a[3], b[0], b[1], b[2], b[3]};
#pragma unroll
            for (int j = 0; j < 8; ++j) ah1[j] = (short)f2b(xx[j]);
        }
#pragma unroll
        for (int ct = 0; ct < 8; ++ct) {
            bfx8 bh = *(const bfx8*)(WTh + (ct * 16 + l) * 128 + k0);
            bfx8 bl = *(const bfx8*)(WTl + (ct * 16 + l) * 128 + k0);
            acc[0][ct] = __builtin_amdgcn_mfma_f32_16x16x32_bf16(ah0, bh, acc[0][ct], 0, 0, 0);
            acc[0][ct] = __builtin_amdgcn_mfma_f32_16x16x32_bf16(ah0, bl, acc[0][ct], 0, 0, 0);
            acc[1][ct] = __builtin_amdgcn_mfma_f32_16x16x32_bf16(ah1, bh, acc[1][ct], 0, 0, 0);
            acc[1][ct] = __builtin_amdgcn_mfma_f32_16x16x32_bf16(ah1, bl, acc[1][ct], 0, 0, 0);
        }
    }
#pragma unroll
    for (int rs = 0; rs < 2; ++rs) {
#pragma unroll
        for (int rr = 0; rr < 4; ++rr) {
            int rw = rbase + rs * 16 + q * 4 + rr;
            if (rw < M) {
                float dv = dinv[rw];
#pragma unroll
                for (int ct = 0; ct < 8; ++ct)
                    G[(size_t)rw * 128 + ct * 16 + l] = f2b(acc[rs][ct][rr] * dv);
            }
        }
    }
}

// ---------- gemm, single bf16-plane A: G = (A @ W) * dinv, bf16 out ----------
__global__ __launch_bounds__(256) void k_gemm1p(
    const u16* __restrict__ Ah,
    const u16* __restrict__ WTh, const u16* __restrict__ WTl,
    const float* __restrict__ dinv, u16* __restrict__ G, int M) {
    const int lane = threadIdx.x & 63;
    const int q = lane >> 4, l = lane & 15;
    int rbase = blockIdx.x * 128 + (threadIdx.x >> 6) * 32;
    if (rbase >= M) return;
    int r0 = rbase + l;      if (r0 >= M) r0 = M - 1;
    int r1 = rbase + 16 + l; if (r1 >= M) r1 = M - 1;

    f32x4 acc[2][8];
#pragma unroll
    for (int i = 0; i < 2; ++i)
#pragma unroll
        for (int j = 0; j < 8; ++j) acc[i][j] = (f32x4){0.f, 0.f, 0.f, 0.f};

#pragma unroll
    for (int kc = 0; kc < 4; ++kc) {
        int k0 = kc * 32 + q * 8;
        bfx8 ah0 = *(const bfx8*)(Ah + (size_t)r0 * 128 + k0);
        bfx8 ah1 = *(const bfx8*)(Ah + (size_t)r1 * 128 + k0);
#pragma unroll
        for (int ct = 0; ct < 8; ++ct) {
            bfx8 bh = *(const bfx8*)(WTh + (ct * 16 + l) * 128 + k0);
            bfx8 bl = *(const bfx8*)(WTl + (ct * 16 + l) * 128 + k0);
            acc[0][ct] = __builtin_amdgcn_mfma_f32_16x16x32_bf16(ah0, bh, acc[0][ct], 0, 0, 0);
            acc[0][ct] = __builtin_amdgcn_mfma_f32_16x16x32_bf16(ah0, bl, acc[0][ct], 0, 0, 0);
            acc[1][ct] = __builtin_amdgcn_mfma_f32_16x16x32_bf16(ah1, bh, acc[1][ct], 0, 0, 0);
            acc[1][ct] = __builtin_amdgcn_mfma_f32_16x16x32_bf16(ah1, bl, acc[1][ct], 0, 0, 0);
        }
    }
#pragma unroll
    for (int rs = 0; rs < 2; ++rs) {
#pragma unroll
        for (int rr = 0; rr < 4; ++rr) {
            int rw = rbase + rs * 16 + q * 4 + rr;
            if (rw < M) {
                float dv = dinv[rw];
#pragma unroll
                for (int ct = 0; ct < 8; ++ct)
                    G[(size_t)rw * 128 + ct * 16 + l] = f2b(acc[rs][ct][rr] * dv);
            }
        }
    }
}

// ---------- GCN aggregate, wave-per-node, 16-unroll (g pre-scaled) ----------
// out[c] = relu(dinv[c]*(g[c] + sum g[src]) + b), bf16 out
__global__ __launch_bounds__(256) void k_agg(
    const uint32* __restrict__ g, const u16* __restrict__ csr,
    const int* __restrict__ off, const int* __restrict__ endo,
    const float* __restrict__ dinv,
    const f32x2* __restrict__ bias, uint32* __restrict__ outH, int n) {
    int w = (blockIdx.x * 256 + threadIdx.x) >> 6;
    if (w >= n) return;
    int lane = threadIdx.x & 63;
    uint32 sv = g[(size_t)w * 64 + lane];
    float s0 = blo(sv), s1 = bhi(sv);
    int e = off[w], e1 = endo[w];
    for (; e + 16 <= e1; e += 16) {
        int ix[16];
#pragma unroll
        for (int j = 0; j < 16; ++j) ix[j] = csr[e + j];
        uint32 vv[16];
#pragma unroll
        for (int j = 0; j < 16; ++j) vv[j] = g[(size_t)ix[j] * 64 + lane];
#pragma unroll
        for (int j = 0; j < 16; ++j) { s0 += blo(vv[j]); s1 += bhi(vv[j]); }
    }
    for (; e + 4 <= e1; e += 4) {
        int ix[4];
#pragma unroll
        for (int j = 0; j < 4; ++j) ix[j] = csr[e + j];
        uint32 vv[4];
#pragma unroll
        for (int j = 0; j < 4; ++j) vv[j] = g[(size_t)ix[j] * 64 + lane];
#pragma unroll
        for (int j = 0; j < 4; ++j) { s0 += blo(vv[j]); s1 += bhi(vv[j]); }
    }
    for (; e < e1; ++e) {
        uint32 v = g[(size_t)csr[e] * 64 + lane];
        s0 += blo(v); s1 += bhi(v);
    }
    float dc = dinv[w];
    f32x2 bb = bias[lane];
    float o0 = fmaxf(fmaf(s0, dc, bb[0]), 0.f);
    float o1 = fmaxf(fmaf(s1, dc, bb[1]), 0.f);
    outH[(size_t)w * 64 + lane] = packbf(o0, o1);
}

// ---------- neighbor mean, wave-per-node, 16-unroll, bf16 out ----------
__global__ __launch_bounds__(256) void k_mean(
    const uint32* __restrict__ h, const u16* __restrict__ csr,
    const int* __restrict__ off, const int* __restrict__ endo,
    uint32* __restrict__ outH, int n) {
    int w = (blockIdx.x * 256 + threadIdx.x) >> 6;
    if (w >= n) return;
    int lane = threadIdx.x & 63;
    int e = off[w], e1 = endo[w];
    int d = e1 - e;
    float s0 = 0.f, s1 = 0.f;
    for (; e + 16 <= e1; e += 16) {
        int ix[16];
#pragma unroll
        for (int j = 0; j < 16; ++j) ix[j] = csr[e + j];
        uint32 vv[16];
#pragma unroll
        for (int j = 0; j < 16; ++j) vv[j] = h[(size_t)ix[j] * 64 + lane];
#pragma unroll
        for (int j = 0; j < 16; ++j) { s0 += blo(vv[j]); s1 += bhi(vv[j]); }
    }
    for (; e + 4 <= e1; e += 4) {
        int ix[4];
#pragma unroll
        for (int j = 0; j < 4; ++j) ix[j] = csr[e + j];
        uint32 vv[4];
#pragma unroll
        for (int j = 0; j < 4; ++j) vv[j] = h[(size_t)ix[j] * 64 + lane];
#pragma unroll
        for (int j = 0; j < 4; ++j) { s0 += blo(vv[j]); s1 += bhi(vv[j]); }
    }
    for (; e < e1; ++e) {
        uint32 v = h[(size_t)csr[e] * 64 + lane];
        s0 += blo(v); s1 += bhi(v);
    }
    float o0, o1;
    if (d > 0) {
        float inv = 1.f / (float)d;
        o0 = s0 * inv; o1 = s1 * inv;
    } else {
        uint32 sv = h[(size_t)w * 64 + lane];
        o0 = blo(sv); o1 = bhi(sv);
    }
    outH[(size_t)w * 64 + lane] = packbf(o0, o1);
}

// ---------- final: out = (w0*h0 + w1*h1 + w2*h2) @ fcW + fc_b ----------
__global__ __launch_bounds__(256) void k_final(
    const u16* __restrict__ h0, const u16* __restrict__ h1,
    const u16* __restrict__ h2, const float* __restrict__ jkw,
    const u16* __restrict__ fcWTh, const u16* __restrict__ fcWTl,
    const float* __restrict__ fcb, float* __restrict__ out, int M) {
    float a0 = jkw[0], a1 = jkw[1], a2 = jkw[2];
    float mx = fmaxf(a0, fmaxf(a1, a2));
    float e0 = expf(a0 - mx), e1 = expf(a1 - mx), e2 = expf(a2 - mx);
    float inv = 1.f / (e0 + e1 + e2);
    float w0 = e0 * inv, w1 = e1 * inv, w2 = e2 * inv;

    const int lane = threadIdx.x & 63;
    const int q = lane >> 4, l = lane & 15;
    int rbase = blockIdx.x * 128 + (threadIdx.x >> 6) * 32;
    if (rbase >= M) return;
    int r0 = rbase + l;      if (r0 >= M) r0 = M - 1;
    int r1 = rbase + 16 + l; if (r1 >= M) r1 = M - 1;

    f32x4 acc[2][4];
#pragma unroll
    for (int i = 0; i < 2; ++i)
#pragma unroll
        for (int j = 0; j < 4; ++j) acc[i][j] = (f32x4){0.f, 0.f, 0.f, 0.f};

    union U8 { bfx8 v; u16 u[8]; };

#pragma unroll
    for (int kc = 0; kc < 4; ++kc) {
        int k0 = kc * 32 + q * 8;
        bfx8 ah[2];
        const int rr2[2] = {r0, r1};
#pragma unroll
        for (int half = 0; half < 2; ++half) {
            size_t o = (size_t)rr2[half] * 128 + k0;
            U8 x0, x1, x2, rh;
            x0.v = *(const bfx8*)(h0 + o);
            x1.v = *(const bfx8*)(h1 + o);
            x2.v = *(const bfx8*)(h2 + o);
#pragma unroll
            for (int j = 0; j < 8; ++j) {
                float c = w0 * b2f(x0.u[j]) + w1 * b2f(x1.u[j]) + w2 * b2f(x2.u[j]);
                rh.u[j] = f2b(c);
            }
            ah[half] = rh.v;
        }
#pragma unroll
        for (int ct = 0; ct < 4; ++ct) {
            bfx8 bh = *(const bfx8*)(fcWTh + (ct * 16 + l) * 128 + k0);
            bfx8 bl = *(const bfx8*)(fcWTl + (ct * 16 + l) * 128 + k0);
#pragma unroll
            for (int half = 0; half < 2; ++half) {
                acc[half][ct] = __builtin_amdgcn_mfma_f32_16x16x32_bf16(ah[half], bh, acc[half][ct], 0, 0, 0);
                acc[half][ct] = __builtin_amdgcn_mfma_f32_16x16x32_bf16(ah[half], bl, acc[half][ct], 0, 0, 0);
            }
        }
    }
#pragma unroll
    for (int rs = 0; rs < 2; ++rs) {
#pragma unroll
        for (int rr = 0; rr < 4; ++rr) {
            int rw = rbase + rs * 16 + q * 4 + rr;
            if (rw < M) {
#pragma unroll
                for (int ct = 0; ct < 4; ++ct) {
                    int cc = ct * 16 + l;
                    out[(size_t)rw * 64 + cc] = acc[rs][ct][rr] + fcb[cc];
                }
            }
        }
    }
}

extern "C" void kernel_launch(void* const* d_in, const int* in_sizes, int n_in,
                              void* d_out, int out_size, void* d_ws, size_t ws_size,
                              hipStream_t stream) {
    const int N = in_sizes[0] / 128;   // 50000
    const int E = in_sizes[1] / 2;     // 800000
    const int NB = (N + 255) >> 8;     // 196 buckets

    const float* x    = (const float*)d_in[0];
    const int* row    = (const int*)d_in[1];
    const int* col    = row + E;
    const float* W1   = (const float*)d_in[2];
    const float* b1   = (const float*)d_in[3];
    const float* W2   = (const float*)d_in[4];
    const float* b2   = (const float*)d_in[5];
    const float* W3   = (const float*)d_in[6];
    const float* b3   = (const float*)d_in[7];
    const float* jkw  = (const float*)d_in[8];
    const float* fcW  = (const float*)d_in[9];
    const float* fcb  = (const float*)d_in[10];
    float* outp       = (float*)d_out;

    char* ws = (char*)d_ws;
    size_t off = 0;
    auto alloc = [&](size_t bytes) -> char* {
        char* p = ws + off;
        off += (bytes + 255) & ~(size_t)255;
        return p;
    };
    int* curC   = (int*)alloc((size_t)NBP * sizeof(int));
    int* curR   = (int*)alloc((size_t)NBP * sizeof(int));
    int* off_in  = (int*)alloc((size_t)N * sizeof(int));
    int* end_in  = (int*)alloc((size_t)N * sizeof(int));
    int* off_out = (int*)alloc((size_t)N * sizeof(int));
    int* end_out = (int*)alloc((size_t)N * sizeof(int));
    uint32* partC = (uint32*)alloc((size_t)NBP * BS * sizeof(uint32));
    uint32* partR = (uint32*)alloc((size_t)NBP * BS * sizeof(uint32));
    u16* csr_src = (u16*)alloc((size_t)NBP * BS * sizeof(u16));
    u16* csr_dst = (u16*)alloc((size_t)NBP * BS * sizeof(u16));
    float* dinv  = (float*)alloc((size_t)N * sizeof(float));
    const int WTN = 3 * 16384 + 8192;
    u16* WTh = (u16*)alloc((size_t)WTN * sizeof(u16));
    u16* WTl = (u16*)alloc((size_t)WTN * sizeof(u16));
    size_t FB = (size_t)N * 128 * sizeof(u16);
    u16* gbuf = (u16*)alloc(FB);
    u16* t0   = (u16*)alloc(FB);
    u16* h0   = (u16*)alloc(FB);
    u16* h1   = (u16*)alloc(FB);
    u16* h2   = (u16*)alloc(FB);

    const int B = 256;
    int Gh = (E + CH - 1) / CH;
    int Gg = (N + 127) / 128;
    int Gwt = (WTN + B - 1) / B;

    k_init<<<1 + Gwt, B, 0, stream>>>(curC, curR, W1, W2, W3, fcW, WTh, WTl, WTN);
    k_partC<<<Gh, B, 0, stream>>>(row, col, E, curC, curR, partC, partR);
    k_fillD<<<2 * NB, B, 0, stream>>>(partC, partR, curC, curR,
                                      off_in, end_in, off_out, end_out,
                                      csr_src, csr_dst, dinv, NB, N);
    k_gemm0<<<Gg, B, 0, stream>>>(x, WTh, WTl, dinv, gbuf, N);

    int aggG = (N + 3) / 4;            // 4 waves/block, 1 node/wave

    // layer 0
    k_agg<<<aggG, B, 0, stream>>>((const uint32*)gbuf, csr_src, off_in, end_in, dinv,
                                  (const f32x2*)b1, (uint32*)t0, N);
    k_mean<<<aggG, B, 0, stream>>>((const uint32*)t0, csr_dst, off_out, end_out,
                                   (uint32*)h0, N);
    // layer 1
    k_gemm1p<<<Gg, B, 0, stream>>>(h0, WTh + 16384, WTl + 16384, dinv, gbuf, N);
    k_agg<<<aggG, B, 0, stream>>>((const uint32*)gbuf, csr_src, off_in, end_in, dinv,
                                  (const f32x2*)b2, (uint32*)h1, N);
    // layer 2
    k_gemm1p<<<Gg, B, 0, stream>>>(h1, WTh + 2 * 16384, WTl + 2 * 16384, dinv, gbuf, N);
    k_agg<<<aggG, B, 0, stream>>>((const uint32*)gbuf, csr_src, off_in, end_in, dinv,
                                  (const f32x2*)b3, (uint32*)h2, N);
    // JK combine + final linear
    k_final<<<Gg, B, 0, stream>>>(h0, h1, h2, jkw,
                                  WTh + 3 * 16384, WTl + 3 * 16384, fcb, outp, N);
}